// Round 1
// baseline (2819.035 us; speedup 1.0000x reference)
//
#include <hip/hip_runtime.h>

#define TPB 256

__global__ void k_deg_init(float* deg, int n) {
    int i = blockIdx.x * blockDim.x + threadIdx.x;
    if (i < n) deg[i] = 1.0f;
}

__global__ void k_deg_acc(const int* __restrict__ dst, float* __restrict__ deg, int e) {
    int i = blockIdx.x * blockDim.x + threadIdx.x;
    if (i < e) atomicAdd(&deg[dst[i]], 1.0f);
}

__global__ void k_dinv(float* deg, int n) {
    int i = blockIdx.x * blockDim.x + threadIdx.x;
    if (i < n) deg[i] = rsqrtf(deg[i]);
}

// g = (x @ W) * dinv[row]; write g to both G and S (S init = self-loop term)
template<int DI, int DO>
__global__ void k_transform(const float* __restrict__ x, const float* __restrict__ W,
                            const float* __restrict__ dinv,
                            float* __restrict__ G, float* __restrict__ S, int n) {
    __shared__ float sW[DI * DO];
    for (int t = threadIdx.x; t < DI * DO; t += blockDim.x) sW[t] = W[t];
    __syncthreads();
    int idx = blockIdx.x * blockDim.x + threadIdx.x;
    if (idx >= n * DO) return;
    int i = idx / DO;
    int f = idx & (DO - 1);
    const float* xr = x + (size_t)i * DI;
    float acc = 0.f;
#pragma unroll
    for (int k = 0; k < DI; ++k) acc += xr[k] * sW[k * DO + f];
    float g = acc * dinv[i];
    G[idx] = g;
    S[idx] = g;
}

// S[dst] += G[src] over all edges; 4 features per thread (float4 gather)
template<int DO>
__global__ void k_scatter(const int* __restrict__ src, const int* __restrict__ dst,
                          const float* __restrict__ G, float* __restrict__ S, int e) {
    constexpr int DOV = DO / 4;
    int idx = blockIdx.x * blockDim.x + threadIdx.x;
    if (idx >= e * DOV) return;
    int ei = idx / DOV;
    int f4 = (idx & (DOV - 1)) * 4;
    int s = src[ei];
    int d = dst[ei];
    const float4 g = *(const float4*)(G + (size_t)s * DO + f4);
    float* sp = S + (size_t)d * DO + f4;
    atomicAdd(sp + 0, g.x);
    atomicAdd(sp + 1, g.y);
    atomicAdd(sp + 2, g.z);
    atomicAdd(sp + 3, g.w);
}

// X = relu(S * dinv[row] + b)
template<int DO>
__global__ void k_finalize(const float* __restrict__ S, const float* __restrict__ dinv,
                           const float* __restrict__ b, float* __restrict__ X, int n) {
    int idx = blockIdx.x * blockDim.x + threadIdx.x;
    if (idx >= n * DO) return;
    int i = idx / DO;
    int f = idx & (DO - 1);
    X[idx] = fmaxf(S[idx] * dinv[i] + b[f], 0.f);
}

// out = relu(x @ W + b)
template<int DI, int DO>
__global__ void k_dense(const float* __restrict__ x, const float* __restrict__ W,
                        const float* __restrict__ b, float* __restrict__ out, int n) {
    __shared__ float sW[DI * DO];
    for (int t = threadIdx.x; t < DI * DO; t += blockDim.x) sW[t] = W[t];
    __syncthreads();
    int idx = blockIdx.x * blockDim.x + threadIdx.x;
    if (idx >= n * DO) return;
    int i = idx / DO;
    int f = idx & (DO - 1);
    const float* xr = x + (size_t)i * DI;
    float acc = b[f];
#pragma unroll
    for (int k = 0; k < DI; ++k) acc += xr[k] * sW[k * DO + f];
    out[idx] = fmaxf(acc, 0.f);
}

static inline int cdiv(int a, int b) { return (a + b - 1) / b; }

extern "C" void kernel_launch(void* const* d_in, const int* in_sizes, int n_in,
                              void* d_out, int out_size, void* d_ws, size_t ws_size,
                              hipStream_t stream) {
    const float* x   = (const float*)d_in[0];
    const int*   ei  = (const int*)d_in[1];
    const float* W1  = (const float*)d_in[2];
    const float* bb1 = (const float*)d_in[3];
    const float* W2  = (const float*)d_in[4];
    const float* bb2 = (const float*)d_in[5];
    const float* W3  = (const float*)d_in[6];
    const float* bb3 = (const float*)d_in[7];
    const float* Wl1 = (const float*)d_in[8];
    const float* bl1 = (const float*)d_in[9];
    const float* Wl2 = (const float*)d_in[10];
    const float* bl2 = (const float*)d_in[11];
    const float* Wl3 = (const float*)d_in[12];
    const float* bl3 = (const float*)d_in[13];
    float* out = (float*)d_out;

    const int n = in_sizes[0] / 16;   // 50000
    const int e = in_sizes[1] / 2;    // 800000
    const int* src = ei;              // edge_index[0]
    const int* dst = ei + e;          // edge_index[1]

    float* ws   = (float*)d_ws;
    float* dinv = ws;
    size_t npad = ((size_t)n + 255) & ~(size_t)255;
    size_t bsz  = (size_t)n * 128;
    float* buf0 = ws + npad;          // G
    float* buf1 = buf0 + bsz;         // S
    float* buf2 = buf1 + bsz;         // X (features between layers)

    // degree (in-degree + self loop) -> dinv = rsqrt(deg), shared by all convs
    k_deg_init<<<cdiv(n, TPB), TPB, 0, stream>>>(dinv, n);
    k_deg_acc<<<cdiv(e, TPB), TPB, 0, stream>>>(dst, dinv, e);
    k_dinv<<<cdiv(n, TPB), TPB, 0, stream>>>(dinv, n);

    // conv1: 16 -> 32
    k_transform<16, 32><<<cdiv(n * 32, TPB), TPB, 0, stream>>>(x, W1, dinv, buf0, buf1, n);
    k_scatter<32><<<cdiv(e * 8, TPB), TPB, 0, stream>>>(src, dst, buf0, buf1, e);
    k_finalize<32><<<cdiv(n * 32, TPB), TPB, 0, stream>>>(buf1, dinv, bb1, buf2, n);

    // conv2: 32 -> 64
    k_transform<32, 64><<<cdiv(n * 64, TPB), TPB, 0, stream>>>(buf2, W2, dinv, buf0, buf1, n);
    k_scatter<64><<<cdiv(e * 16, TPB), TPB, 0, stream>>>(src, dst, buf0, buf1, e);
    k_finalize<64><<<cdiv(n * 64, TPB), TPB, 0, stream>>>(buf1, dinv, bb2, buf2, n);

    // conv3: 64 -> 128
    k_transform<64, 128><<<cdiv(n * 128, TPB), TPB, 0, stream>>>(buf2, W3, dinv, buf0, buf1, n);
    k_scatter<128><<<cdiv(e * 32, TPB), TPB, 0, stream>>>(src, dst, buf0, buf1, e);
    k_finalize<128><<<cdiv(n * 128, TPB), TPB, 0, stream>>>(buf1, dinv, bb3, buf2, n);

    // dense head: 128 -> 64 -> 32 -> 16
    k_dense<128, 64><<<cdiv(n * 64, TPB), TPB, 0, stream>>>(buf2, Wl1, bl1, buf0, n);
    k_dense<64, 32><<<cdiv(n * 32, TPB), TPB, 0, stream>>>(buf0, Wl2, bl2, buf1, n);
    k_dense<32, 16><<<cdiv(n * 16, TPB), TPB, 0, stream>>>(buf1, Wl3, bl3, out, n);
}

// Round 2
// 612.797 us; speedup vs baseline: 4.6003x; 4.6003x over previous
//
#include <hip/hip_runtime.h>

#define TPB 256

static inline int cdiv(int a, int b) { return (a + b - 1) / b; }

__global__ void k_zero_int(int* p, int n) {
    int i = blockIdx.x * blockDim.x + threadIdx.x;
    if (i < n) p[i] = 0;
}

__global__ void k_hist(const int* __restrict__ dst, int* __restrict__ cnt, int e) {
    int i = blockIdx.x * blockDim.x + threadIdx.x;
    if (i < e) atomicAdd(&cnt[dst[i]], 1);
}

__global__ void k_dinv_from_cnt(const int* __restrict__ cnt, float* __restrict__ dinv, int n) {
    int i = blockIdx.x * blockDim.x + threadIdx.x;
    if (i < n) dinv[i] = rsqrtf((float)cnt[i] + 1.0f);  // +1 self-loop
}

// exclusive scan, phase 1: per-256-block scan, emit block sums
__global__ void k_scan1(const int* __restrict__ cnt, int* __restrict__ offs,
                        int* __restrict__ bsum, int n) {
    __shared__ int s[256];
    int i = blockIdx.x * 256 + threadIdx.x;
    int v = (i < n) ? cnt[i] : 0;
    s[threadIdx.x] = v;
    __syncthreads();
    for (int d = 1; d < 256; d <<= 1) {
        int t = (threadIdx.x >= d) ? s[threadIdx.x - d] : 0;
        __syncthreads();
        s[threadIdx.x] += t;
        __syncthreads();
    }
    if (i < n) offs[i] = s[threadIdx.x] - v;          // exclusive
    if (threadIdx.x == 255) bsum[blockIdx.x] = s[255];
}

// phase 2: single-block exclusive scan of block sums (nb <= 256)
__global__ void k_scan2(int* __restrict__ bsum, int nb) {
    __shared__ int s[256];
    int v = (threadIdx.x < nb) ? bsum[threadIdx.x] : 0;
    s[threadIdx.x] = v;
    __syncthreads();
    for (int d = 1; d < 256; d <<= 1) {
        int t = (threadIdx.x >= d) ? s[threadIdx.x - d] : 0;
        __syncthreads();
        s[threadIdx.x] += t;
        __syncthreads();
    }
    if (threadIdx.x < nb) bsum[threadIdx.x] = s[threadIdx.x] - v;
}

// phase 3: add block offsets; init cursor; cap offs[n] = e
__global__ void k_scan3(int* __restrict__ offs, const int* __restrict__ bsum,
                        int* __restrict__ cursor, int n, int e) {
    int i = blockIdx.x * blockDim.x + threadIdx.x;
    if (i < n) {
        int v = offs[i] + bsum[i >> 8];
        offs[i] = v;
        cursor[i] = v;
    }
    if (i == 0) offs[n] = e;
}

// bucket edges by dst: ssrc[CSR position] = src
__global__ void k_fill(const int* __restrict__ src, const int* __restrict__ dst,
                       int* __restrict__ cursor, int* __restrict__ ssrc, int e) {
    int i = blockIdx.x * blockDim.x + threadIdx.x;
    if (i < e) {
        int pos = atomicAdd(&cursor[dst[i]], 1);
        ssrc[pos] = src[i];
    }
}

// G = (x @ W) * dinv[row]
template<int DI, int DO>
__global__ void k_transform(const float* __restrict__ x, const float* __restrict__ W,
                            const float* __restrict__ dinv, float* __restrict__ G, int n) {
    __shared__ float sW[DI * DO];
    for (int t = threadIdx.x; t < DI * DO; t += blockDim.x) sW[t] = W[t];
    __syncthreads();
    int idx = blockIdx.x * blockDim.x + threadIdx.x;
    if (idx >= n * DO) return;
    int i = idx / DO;
    int f = idx & (DO - 1);
    const float* xr = x + (size_t)i * DI;
    float acc = 0.f;
#pragma unroll
    for (int k = 0; k < DI; ++k) acc += xr[k] * sW[k * DO + f];
    G[idx] = acc * dinv[i];
}

// X = relu((G[i] + sum_{j in N(i)} G[src_j]) * dinv[i] + b)   — CSR gather, no atomics
template<int DO>
__global__ void k_gather(const int* __restrict__ offs, const int* __restrict__ ssrc,
                         const float* __restrict__ G, const float* __restrict__ dinv,
                         const float* __restrict__ b, float* __restrict__ X, int n) {
    constexpr int C = DO / 4;
    int idx = blockIdx.x * blockDim.x + threadIdx.x;
    if (idx >= n * C) return;
    int i = idx / C;
    int c = idx & (C - 1);
    int f4 = c * 4;
    float4 acc = *(const float4*)(G + (size_t)i * DO + f4);   // self-loop term
    int s0 = offs[i], s1 = offs[i + 1];
    for (int j = s0; j < s1; ++j) {
        int s = ssrc[j];                                       // uniform across chunk threads
        const float4 g = *(const float4*)(G + (size_t)s * DO + f4);
        acc.x += g.x; acc.y += g.y; acc.z += g.z; acc.w += g.w;
    }
    float di = dinv[i];
    float4 o;
    o.x = fmaxf(acc.x * di + b[f4 + 0], 0.f);
    o.y = fmaxf(acc.y * di + b[f4 + 1], 0.f);
    o.z = fmaxf(acc.z * di + b[f4 + 2], 0.f);
    o.w = fmaxf(acc.w * di + b[f4 + 3], 0.f);
    *(float4*)(X + (size_t)i * DO + f4) = o;
}

// out = relu(x @ W + b)
template<int DI, int DO>
__global__ void k_dense(const float* __restrict__ x, const float* __restrict__ W,
                        const float* __restrict__ b, float* __restrict__ out, int n) {
    __shared__ float sW[DI * DO];
    for (int t = threadIdx.x; t < DI * DO; t += blockDim.x) sW[t] = W[t];
    __syncthreads();
    int idx = blockIdx.x * blockDim.x + threadIdx.x;
    if (idx >= n * DO) return;
    int i = idx / DO;
    int f = idx & (DO - 1);
    const float* xr = x + (size_t)i * DI;
    float acc = b[f];
#pragma unroll
    for (int k = 0; k < DI; ++k) acc += xr[k] * sW[k * DO + f];
    out[idx] = fmaxf(acc, 0.f);
}

extern "C" void kernel_launch(void* const* d_in, const int* in_sizes, int n_in,
                              void* d_out, int out_size, void* d_ws, size_t ws_size,
                              hipStream_t stream) {
    const float* x   = (const float*)d_in[0];
    const int*   ei  = (const int*)d_in[1];
    const float* W1  = (const float*)d_in[2];
    const float* bb1 = (const float*)d_in[3];
    const float* W2  = (const float*)d_in[4];
    const float* bb2 = (const float*)d_in[5];
    const float* W3  = (const float*)d_in[6];
    const float* bb3 = (const float*)d_in[7];
    const float* Wl1 = (const float*)d_in[8];
    const float* bl1 = (const float*)d_in[9];
    const float* Wl2 = (const float*)d_in[10];
    const float* bl2 = (const float*)d_in[11];
    const float* Wl3 = (const float*)d_in[12];
    const float* bl3 = (const float*)d_in[13];
    float* out = (float*)d_out;

    const int n = in_sizes[0] / 16;   // 50000
    const int e = in_sizes[1] / 2;    // 800000
    const int* src = ei;
    const int* dst = ei + e;

    // ---- workspace layout (256B-aligned chunks) ----
    char* p = (char*)d_ws;
    auto alloc = [&](size_t bytes) {
        char* r = p;
        p += (bytes + 255) & ~(size_t)255;
        return r;
    };
    const int nb = cdiv(n, 256);                      // scan blocks (196)
    float* dinv   = (float*)alloc((size_t)n * 4);
    int*   cnt    = (int*)  alloc((size_t)n * 4);
    int*   offs   = (int*)  alloc((size_t)(n + 1) * 4);
    int*   cursor = (int*)  alloc((size_t)n * 4);
    int*   bsum   = (int*)  alloc(256 * 4);
    int*   ssrc   = (int*)  alloc((size_t)e * 4);
    float* G      = (float*)alloc((size_t)n * 128 * 4);
    float* X      = (float*)alloc((size_t)n * 128 * 4);

    // ---- CSR build + dinv (graph is identical every call; rebuilt each call) ----
    k_zero_int<<<cdiv(n, TPB), TPB, 0, stream>>>(cnt, n);
    k_hist<<<cdiv(e, TPB), TPB, 0, stream>>>(dst, cnt, e);
    k_dinv_from_cnt<<<cdiv(n, TPB), TPB, 0, stream>>>(cnt, dinv, n);
    k_scan1<<<nb, 256, 0, stream>>>(cnt, offs, bsum, n);
    k_scan2<<<1, 256, 0, stream>>>(bsum, nb);
    k_scan3<<<cdiv(n, TPB), TPB, 0, stream>>>(offs, bsum, cursor, n, e);
    k_fill<<<cdiv(e, TPB), TPB, 0, stream>>>(src, dst, cursor, ssrc, e);

    // ---- conv1: 16 -> 32 ----
    k_transform<16, 32><<<cdiv(n * 32, TPB), TPB, 0, stream>>>(x, W1, dinv, G, n);
    k_gather<32><<<cdiv(n * 8, TPB), TPB, 0, stream>>>(offs, ssrc, G, dinv, bb1, X, n);

    // ---- conv2: 32 -> 64 ----
    k_transform<32, 64><<<cdiv(n * 64, TPB), TPB, 0, stream>>>(X, W2, dinv, G, n);
    k_gather<64><<<cdiv(n * 16, TPB), TPB, 0, stream>>>(offs, ssrc, G, dinv, bb2, X, n);

    // ---- conv3: 64 -> 128 ----
    k_transform<64, 128><<<cdiv(n * 128, TPB), TPB, 0, stream>>>(X, W3, dinv, G, n);
    k_gather<128><<<cdiv(n * 32, TPB), TPB, 0, stream>>>(offs, ssrc, G, dinv, bb3, X, n);

    // ---- dense head: 128 -> 64 -> 32 -> 16 (reuse G/X as ping-pong) ----
    k_dense<128, 64><<<cdiv(n * 64, TPB), TPB, 0, stream>>>(X, Wl1, bl1, G, n);
    k_dense<64, 32><<<cdiv(n * 32, TPB), TPB, 0, stream>>>(G, Wl2, bl2, X, n);
    k_dense<32, 16><<<cdiv(n * 16, TPB), TPB, 0, stream>>>(X, Wl3, bl3, out, n);
}